// Round 1
// baseline (310.121 us; speedup 1.0000x reference)
//
#include <hip/hip_runtime.h>

#define DEV static __device__ __forceinline__

typedef __attribute__((ext_vector_type(8))) __bf16 bf16x8;
typedef __attribute__((ext_vector_type(4))) float f32x4;

constexpr int CB = 2;     // batch
constexpr int CS = 2048;  // seq
constexpr int CE = 1024;  // embed
constexpr int CH = 16;    // heads
constexpr int CD = 64;    // head dim

DEV unsigned short f2bf(float x) {  // RNE f32 -> bf16 bits
  unsigned int u = __float_as_uint(x);
  u += 0x7fffu + ((u >> 16) & 1u);
  return (unsigned short)(u >> 16);
}

DEV f32x4 mfma16(bf16x8 a, bf16x8 b, f32x4 c) {
  return __builtin_amdgcn_mfma_f32_16x16x32_bf16(a, b, c, 0, 0, 0);
}

// ---------------- f32 -> bf16 convert (vectorized 8/thread) ----------------
__global__ __launch_bounds__(256) void cvt_bf16(const float* __restrict__ in,
                                                unsigned short* __restrict__ out, int n) {
  int i = (blockIdx.x * 256 + threadIdx.x) * 8;
  if (i >= n) return;
  float4 a = *reinterpret_cast<const float4*>(in + i);
  float4 b = *reinterpret_cast<const float4*>(in + i + 4);
  uint4 v;
  v.x = (unsigned int)f2bf(a.x) | ((unsigned int)f2bf(a.y) << 16);
  v.y = (unsigned int)f2bf(a.z) | ((unsigned int)f2bf(a.w) << 16);
  v.z = (unsigned int)f2bf(b.x) | ((unsigned int)f2bf(b.y) << 16);
  v.w = (unsigned int)f2bf(b.z) | ((unsigned int)f2bf(b.w) << 16);
  *reinterpret_cast<uint4*>(out + i) = v;
}

// ---------------- GEMM: C[M,N] = A[M,K] @ W[N,K]^T + bias[N] ----------------
// OM 0: bf16 row-major [M,N]
// OM 1: f32  row-major [M,N]
// OM 2: bf16 V^T layout: (m=(b,s), n=(h,d)) -> out[((b*H+h)*DK+d)*S + s]
// 128x128 tile, BK=64, 4 waves (2x2), each wave 64x64 = 4x4 frags of 16x16.
template<int OM>
__global__ __launch_bounds__(256) void gemm_bt(const unsigned short* __restrict__ A,
                                               const unsigned short* __restrict__ W,
                                               const float* __restrict__ bias,
                                               void* __restrict__ out,
                                               int M, int N, int K) {
  __shared__ __align__(16) unsigned short As[128][72];  // +8 pad: kills 8-way bank conflict
  __shared__ __align__(16) unsigned short Bs[128][72];
  const int tid = threadIdx.x;
  const int lane = tid & 63, wave = tid >> 6;
  const int wm = (wave >> 1) * 64, wn = (wave & 1) * 64;
  const int g = lane >> 4, rr = lane & 15;
  const int m0 = blockIdx.x * 128, n0 = blockIdx.y * 128;
  f32x4 acc[4][4] = {};

  for (int k0 = 0; k0 < K; k0 += 64) {
    // stage 128x64 bf16 of A and W (each thread: 4 x 16B per matrix)
#pragma unroll
    for (int t = 0; t < 4; t++) {
      const int cid = tid + t * 256;
      const int row = cid >> 3, col = (cid & 7) * 8;
      *reinterpret_cast<uint4*>(&As[row][col]) =
          *reinterpret_cast<const uint4*>(A + (long)(m0 + row) * K + k0 + col);
      *reinterpret_cast<uint4*>(&Bs[row][col]) =
          *reinterpret_cast<const uint4*>(W + (long)(n0 + row) * K + k0 + col);
    }
    __syncthreads();
#pragma unroll
    for (int kk = 0; kk < 2; kk++) {
      bf16x8 af[4], bfr[4];
#pragma unroll
      for (int i = 0; i < 4; i++)
        af[i] = *reinterpret_cast<const bf16x8*>(&As[wm + i * 16 + rr][kk * 32 + g * 8]);
#pragma unroll
      for (int j = 0; j < 4; j++)
        bfr[j] = *reinterpret_cast<const bf16x8*>(&Bs[wn + j * 16 + rr][kk * 32 + g * 8]);
#pragma unroll
      for (int i = 0; i < 4; i++)
#pragma unroll
        for (int j = 0; j < 4; j++)
          acc[i][j] = mfma16(af[i], bfr[j], acc[i][j]);
    }
    __syncthreads();
  }

  // epilogue: C frag layout col=lane&15, row=(lane>>4)*4+reg (m89-verified)
#pragma unroll
  for (int i = 0; i < 4; i++) {
#pragma unroll
    for (int j = 0; j < 4; j++) {
      const int colg = n0 + wn + j * 16 + rr;
      const float bv = bias[colg];
      if (OM == 2) {
        const int rowbase = m0 + wm + i * 16 + g * 4;  // 4 consecutive s
        const int bb = rowbase >> 11, s = rowbase & 2047;
        const int hh = colg >> 6, d = colg & 63;
        uint2 val;
        val.x = (unsigned int)f2bf(acc[i][j][0] + bv) | ((unsigned int)f2bf(acc[i][j][1] + bv) << 16);
        val.y = (unsigned int)f2bf(acc[i][j][2] + bv) | ((unsigned int)f2bf(acc[i][j][3] + bv) << 16);
        *reinterpret_cast<uint2*>((unsigned short*)out +
                                  ((long)((bb * CH + hh) * CD + d)) * CS + s) = val;
      } else {
#pragma unroll
        for (int r = 0; r < 4; r++) {
          const int row = m0 + wm + i * 16 + g * 4 + r;
          const float v = acc[i][j][r] + bv;
          if (OM == 0) ((unsigned short*)out)[(long)row * N + colg] = f2bf(v);
          else         ((float*)out)[(long)row * N + colg] = v;
        }
      }
    }
  }
}

// ---------------- Flash attention ----------------
// grid (S/128, H, B); 4 waves x 32 q-rows. KB=32 keys/iter.
// K/V/bias read direct from global (L2-resident per (b,h)); V pre-transposed.
__global__ __launch_bounds__(256) void attn_kernel(const unsigned short* __restrict__ Qb,
                                                   const unsigned short* __restrict__ Kb,
                                                   const unsigned short* __restrict__ Vt,
                                                   const float* __restrict__ bias,
                                                   const int* __restrict__ mask,
                                                   unsigned short* __restrict__ AO) {
  __shared__ __align__(16) unsigned short Plds[4][32][40];  // per-wave P, +8 pad
  const int qt = blockIdx.x, h = blockIdx.y, b = blockIdx.z;
  const int tid = threadIdx.x;
  const int lane = tid & 63, wave = tid >> 6;
  const int g = lane >> 4, c = lane & 15;
  const int q0 = qt * 128 + wave * 32;

  // Q fragments (A-layout: row=lane&15, k=(lane>>4)*8+j)
  bf16x8 qf[2][2];
  {
    const unsigned short* Qbase = Qb + ((long)b * CS + q0) * CE + h * CD;
#pragma unroll
    for (int qb = 0; qb < 2; qb++)
#pragma unroll
      for (int kd = 0; kd < 2; kd++)
        qf[qb][kd] = *reinterpret_cast<const bf16x8*>(Qbase + (long)(qb * 16 + c) * CE + kd * 32 + g * 8);
  }
  int mq[2][4];
  const float* brow[2][4];
#pragma unroll
  for (int qb = 0; qb < 2; qb++)
#pragma unroll
    for (int r = 0; r < 4; r++) {
      const int qrow = q0 + qb * 16 + g * 4 + r;  // C-frag row for this lane
      mq[qb][r] = mask[b * CS + qrow];
      brow[qb][r] = bias + ((long)b * CS + qrow) * CS + c;
    }
  const unsigned short* Kbase = Kb + (long)b * CS * CE + h * CD;
  const unsigned short* Vbase = Vt + (long)(b * CH + h) * CD * CS;

  f32x4 o[2][4] = {};
  float mrun[2][4], lrun[2][4];
#pragma unroll
  for (int qb = 0; qb < 2; qb++)
#pragma unroll
    for (int r = 0; r < 4; r++) { mrun[qb][r] = -__builtin_inff(); lrun[qb][r] = 0.f; }

  for (int kt = 0; kt < CS; kt += 32) {
    // ---- S = Q K^T ----
    f32x4 sf[2][2] = {};
#pragma unroll
    for (int kd = 0; kd < 2; kd++) {
      bf16x8 kf[2];
#pragma unroll
      for (int cb = 0; cb < 2; cb++)
        kf[cb] = *reinterpret_cast<const bf16x8*>(Kbase + (long)(kt + cb * 16 + c) * CE + kd * 32 + g * 8);
#pragma unroll
      for (int qb = 0; qb < 2; qb++)
#pragma unroll
        for (int cb = 0; cb < 2; cb++)
          sf[qb][cb] = mfma16(qf[qb][kd], kf[cb], sf[qb][cb]);
    }
    // ---- scores: *1/8 + bias, mask -> -1e9 (exact, matches ref semantics) ----
    const int mk0 = mask[b * CS + kt + c];
    const int mk1 = mask[b * CS + kt + 16 + c];
    float pv[2][2][4];
#pragma unroll
    for (int qb = 0; qb < 2; qb++)
#pragma unroll
      for (int cb = 0; cb < 2; cb++) {
        const int mkc = cb ? mk1 : mk0;
#pragma unroll
        for (int r = 0; r < 4; r++) {
          const float sval = sf[qb][cb][r] * 0.125f + brow[qb][r][kt + cb * 16];
          pv[qb][cb][r] = (mq[qb][r] != 0 && mkc != 0) ? sval : -1e9f;
        }
      }
    // ---- online softmax ----
    float tmax[2][4];
#pragma unroll
    for (int qb = 0; qb < 2; qb++)
#pragma unroll
      for (int r = 0; r < 4; r++) tmax[qb][r] = fmaxf(pv[qb][0][r], pv[qb][1][r]);
#pragma unroll
    for (int xm = 1; xm <= 8; xm <<= 1)
#pragma unroll
      for (int qb = 0; qb < 2; qb++)
#pragma unroll
        for (int r = 0; r < 4; r++)
          tmax[qb][r] = fmaxf(tmax[qb][r], __shfl_xor(tmax[qb][r], xm, 64));
    float sc[2][4];
#pragma unroll
    for (int qb = 0; qb < 2; qb++)
#pragma unroll
      for (int r = 0; r < 4; r++) {
        const float nm = fmaxf(mrun[qb][r], tmax[qb][r]);
        sc[qb][r] = __expf(mrun[qb][r] - nm);  // -inf first iter -> 0
        mrun[qb][r] = nm;
        lrun[qb][r] *= sc[qb][r];
      }
#pragma unroll
    for (int qb = 0; qb < 2; qb++)
#pragma unroll
      for (int nb = 0; nb < 4; nb++) {
        f32x4 t = o[qb][nb];
#pragma unroll
        for (int r = 0; r < 4; r++) t[r] *= sc[qb][r];
        o[qb][nb] = t;
      }
    float rs[2][4] = {};
#pragma unroll
    for (int qb = 0; qb < 2; qb++)
#pragma unroll
      for (int cb = 0; cb < 2; cb++)
#pragma unroll
        for (int r = 0; r < 4; r++) {
          const float p = __expf(pv[qb][cb][r] - mrun[qb][r]);
          rs[qb][r] += p;
          Plds[wave][qb * 16 + g * 4 + r][cb * 16 + c] = f2bf(p);
        }
#pragma unroll
    for (int xm = 1; xm <= 8; xm <<= 1)
#pragma unroll
      for (int qb = 0; qb < 2; qb++)
#pragma unroll
        for (int r = 0; r < 4; r++)
          rs[qb][r] += __shfl_xor(rs[qb][r], xm, 64);
#pragma unroll
    for (int qb = 0; qb < 2; qb++)
#pragma unroll
      for (int r = 0; r < 4; r++) lrun[qb][r] += rs[qb][r];
    __syncthreads();  // P writes -> P reads (wave-private, but be safe)
    // ---- O += P V ----
    bf16x8 pa[2], vf[4];
#pragma unroll
    for (int qb = 0; qb < 2; qb++)
      pa[qb] = *reinterpret_cast<const bf16x8*>(&Plds[wave][qb * 16 + c][g * 8]);
#pragma unroll
    for (int nb = 0; nb < 4; nb++)
      vf[nb] = *reinterpret_cast<const bf16x8*>(Vbase + (long)(nb * 16 + c) * CS + kt + g * 8);
#pragma unroll
    for (int qb = 0; qb < 2; qb++)
#pragma unroll
      for (int nb = 0; nb < 4; nb++)
        o[qb][nb] = mfma16(pa[qb], vf[nb], o[qb][nb]);
  }
  // ---- normalize + store bf16 [B,S,E] ----
#pragma unroll
  for (int qb = 0; qb < 2; qb++) {
    float linv[4];
#pragma unroll
    for (int r = 0; r < 4; r++) linv[r] = 1.0f / lrun[qb][r];
#pragma unroll
    for (int nb = 0; nb < 4; nb++)
#pragma unroll
      for (int r = 0; r < 4; r++)
        AO[((long)b * CS + q0 + qb * 16 + g * 4 + r) * CE + h * CD + nb * 16 + c] =
            f2bf(o[qb][nb][r] * linv[r]);
  }
}

// ---------------- host ----------------
extern "C" void kernel_launch(void* const* d_in, const int* in_sizes, int n_in,
                              void* d_out, int out_size, void* d_ws, size_t ws_size,
                              hipStream_t stream) {
  (void)in_sizes; (void)n_in; (void)out_size; (void)ws_size;
  const float* x    = (const float*)d_in[0];
  const float* kv   = (const float*)d_in[1];
  const int*   mask = (const int*)d_in[2];
  const float* ab   = (const float*)d_in[3];
  const float* WQw  = (const float*)d_in[4];
  const float* WQb  = (const float*)d_in[5];
  const float* WKw  = (const float*)d_in[6];
  const float* WKb  = (const float*)d_in[7];
  const float* WVw  = (const float*)d_in[8];
  const float* WVb  = (const float*)d_in[9];
  const float* WOw  = (const float*)d_in[10];
  const float* WOb  = (const float*)d_in[11];
  float* out = (float*)d_out;

  const long NE = (long)CB * CS * CE;  // 4,194,304
  const long WE = (long)CE * CE;       // 1,048,576
  unsigned short* ws  = (unsigned short*)d_ws;  // total use: 56 MB
  unsigned short* xb  = ws;
  unsigned short* kvb = xb + NE;
  unsigned short* wqb = kvb + NE;
  unsigned short* wkb = wqb + WE;
  unsigned short* wvb = wkb + WE;
  unsigned short* wob = wvb + WE;
  unsigned short* Qb  = wob + WE;
  unsigned short* Kb  = Qb + NE;
  unsigned short* Vt  = Kb + NE;   // [B,H,DK,S]
  unsigned short* AO  = Vt + NE;

  cvt_bf16<<<(int)(NE / 2048), 256, 0, stream>>>(x,   xb,  (int)NE);
  cvt_bf16<<<(int)(NE / 2048), 256, 0, stream>>>(kv,  kvb, (int)NE);
  cvt_bf16<<<(int)(WE / 2048), 256, 0, stream>>>(WQw, wqb, (int)WE);
  cvt_bf16<<<(int)(WE / 2048), 256, 0, stream>>>(WKw, wkb, (int)WE);
  cvt_bf16<<<(int)(WE / 2048), 256, 0, stream>>>(WVw, wvb, (int)WE);
  cvt_bf16<<<(int)(WE / 2048), 256, 0, stream>>>(WOw, wob, (int)WE);

  dim3 gg(32, 8, 1), gb(256, 1, 1);
  gemm_bt<0><<<gg, gb, 0, stream>>>(xb,  wqb, WQb, Qb,  CB * CS, CE, CE);
  gemm_bt<0><<<gg, gb, 0, stream>>>(kvb, wkb, WKb, Kb,  CB * CS, CE, CE);
  gemm_bt<2><<<gg, gb, 0, stream>>>(kvb, wvb, WVb, Vt,  CB * CS, CE, CE);

  attn_kernel<<<dim3(CS / 128, CH, CB), 256, 0, stream>>>(Qb, Kb, Vt, ab, mask, AO);

  gemm_bt<1><<<gg, gb, 0, stream>>>(AO, wob, WOb, out, CB * CS, CE, CE);
}